// Round 14
// baseline (197.716 us; speedup 1.0000x reference)
//
#include <hip/hip_runtime.h>

#define T_TOKENS 16384
#define DIM 2048
#define NE 8
#define QOUT 2048
#define LSCALE 2.0f

typedef __attribute__((ext_vector_type(4))) float f32x4;
typedef __attribute__((ext_vector_type(8))) short s16x8;
typedef __attribute__((ext_vector_type(4))) short s16x4;

__device__ __forceinline__ short f2bf(float f) {
  unsigned u = __builtin_bit_cast(unsigned, f);
  u += 0x7fffu + ((u >> 16) & 1u);   // round-to-nearest-even
  return (short)(u >> 16);
}

__device__ __forceinline__ void barrier_lds() {
  asm volatile("s_waitcnt lgkmcnt(0)" ::: "memory");
  __builtin_amdgcn_s_barrier();
}

// ---------------------------------------------------------------------------
// Pack LoRA weights (f32) into bf16 MFMA-fragment layout.
// lora_a [E][D][R]  -> P1[d8][col=e*16+r][j]  (d = d8*8+j), col in [0,128)
// lora_b [E][R][QO] -> P2[k8][c][j]           (k = k8*8+j = e*16+r)
// ---------------------------------------------------------------------------
__global__ __launch_bounds__(256) void k_pack(
    const float* __restrict__ qa, const float* __restrict__ qb,
    const float* __restrict__ va, const float* __restrict__ vb,
    short* __restrict__ Bq1, short* __restrict__ Bv1,
    short* __restrict__ Bq2, short* __restrict__ Bv2) {
  int tid = blockIdx.x * 256 + threadIdx.x;  // 131072 threads
  if (tid < 65536) {
    int mat = tid >> 15;
    int idx = tid & 32767;          // d8*128 + col
    int d8 = idx >> 7, c = idx & 127;
    int e = c >> 4, r = c & 15;
    const float* src = mat ? va : qa;
    short* dst = mat ? Bv1 : Bq1;
    s16x8 v;
#pragma unroll
    for (int j = 0; j < 8; ++j)
      v[j] = f2bf(src[((size_t)e * DIM + d8 * 8 + j) * 16 + r]);
    *(s16x8*)(dst + (size_t)idx * 8) = v;
  } else {
    int t2 = tid - 65536;
    int mat = t2 >> 15;
    int idx = t2 & 32767;           // k8*2048 + c
    int k8 = idx >> 11, c = idx & 2047;
    const float* src = mat ? vb : qb;
    short* dst = mat ? Bv2 : Bq2;
    s16x8 v;
#pragma unroll
    for (int j = 0; j < 8; ++j)
      v[j] = f2bf(src[(size_t)(k8 * 8 + j) * QOUT + c]);
    *(s16x8*)(dst + (size_t)idx * 8) = v;
  }
}

// ---------------------------------------------------------------------------
// Stage 1 + routing: low = (h @ Acat) * w, bf16 out to global [T][128] x2.
// 16-token blocks, 256 threads (4 waves), grid 1024 -> 4 blocks/CU,
// 16 waves/CU.  LDS 5 KB.  One barrier per K-step, 4-block interleave.
// Phase A as R13: thread (r=tid>>4, kq=(tid&15)*4) stages one float4 of the
// 16x64 h tile into At (dbuf bf16); all-8-expert routing partials vs global
// rw (f32-exact); wave wv owns 64 concat cols.  Epilogue: 16-lane shfl
// reduce -> per-thread softmax/top-2 -> wl -> scale -> global store.
// ---------------------------------------------------------------------------
__global__ __launch_bounds__(256) void k_s1(
    const float* __restrict__ h, const float* __restrict__ rw,
    const short* __restrict__ Bq1, const short* __restrict__ Bv1,
    short* __restrict__ lowq, short* __restrict__ lowv) {
  __shared__ short At[2][16][72];   // 16 tok x 64 k bf16, 144B rows (4.5 KB)
  __shared__ float wl[16][NE];      // 0.5 KB

  const int tid = threadIdx.x;
  const int lane = tid & 63, wv = tid >> 6;
  const int lrow = lane & 15, lk = lane >> 4;
  const int row0 = blockIdx.x * 16;
  const int r  = tid >> 4;              // 0..15: token row this thread stages
  const int kq = (tid & 15) * 4;        // k-offset within 64-wide step

  const float* hrow = h + (size_t)(row0 + r) * DIM + kq;
  const short* B1 = (wv >= 2) ? Bv1 : Bq1;
  int cc[4];
#pragma unroll
  for (int ct = 0; ct < 4; ++ct) cc[ct] = (wv & 1) * 64 + ct * 16 + lrow;

  float4 hv = *(const float4*)(hrow);   // depth-1 prefetch

  float lg[NE] = {0.f, 0.f, 0.f, 0.f, 0.f, 0.f, 0.f, 0.f};
  f32x4 acc1[4] = {};

#pragma unroll 1
  for (int kb = 0; kb < DIM; kb += 64) {
    const int cur = (kb >> 6) & 1;
    float4 hvn = *(const float4*)(hrow + ((kb + 64) & (DIM - 1)));  // dead on tail
    s16x8 bA[4], bB[4];
#pragma unroll
    for (int ct = 0; ct < 4; ++ct) {
      int d8 = (kb >> 3) + lk;
      bA[ct] = *(const s16x8*)(B1 + ((size_t)d8 * 128 + cc[ct]) * 8);
      bB[ct] = *(const s16x8*)(B1 + ((size_t)(d8 + 4) * 128 + cc[ct]) * 8);
    }
    s16x4 hb4;
    hb4[0] = f2bf(hv.x); hb4[1] = f2bf(hv.y);
    hb4[2] = f2bf(hv.z); hb4[3] = f2bf(hv.w);
    *(s16x4*)&At[cur][r][kq] = hb4;
#pragma unroll 1
    for (int g = 0; g < 2; ++g) {
#pragma unroll
      for (int e = 0; e < 4; ++e) {
        float4 rv = *(const float4*)(rw + (g * 4 + e) * DIM + kb + kq);
        lg[g * 4 + e] += hv.x * rv.x + hv.y * rv.y + hv.z * rv.z + hv.w * rv.w;
      }
    }
    barrier_lds();                       // lgkm drain only; vmcnt stays
    s16x8 a0 = *(const s16x8*)&At[cur][lrow][lk * 8];
    s16x8 a1 = *(const s16x8*)&At[cur][lrow][32 + lk * 8];
#pragma unroll
    for (int ct = 0; ct < 4; ++ct) {
      acc1[ct] = __builtin_amdgcn_mfma_f32_16x16x32_bf16(bA[ct], a0, acc1[ct], 0, 0, 0);
      acc1[ct] = __builtin_amdgcn_mfma_f32_16x16x32_bf16(bB[ct], a1, acc1[ct], 0, 0, 0);
    }
    hv = hvn;
  }

  // reduce logits across the 16 k-lanes of each token row
#pragma unroll
  for (int e = 0; e < NE; ++e) {
    lg[e] += __shfl_xor(lg[e], 1, 64);
    lg[e] += __shfl_xor(lg[e], 2, 64);
    lg[e] += __shfl_xor(lg[e], 4, 64);
    lg[e] += __shfl_xor(lg[e], 8, 64);
  }
  // softmax + top-2 (redundant across the 16 lanes of a row; deterministic)
  float mx = lg[0];
#pragma unroll
  for (int e = 1; e < NE; ++e) mx = fmaxf(mx, lg[e]);
  float p[NE], sum = 0.f;
#pragma unroll
  for (int e = 0; e < NE; ++e) { p[e] = expf(lg[e] - mx); sum += p[e]; }
  int i1 = 0; float v1 = p[0];
#pragma unroll
  for (int e = 1; e < NE; ++e) if (p[e] > v1) { v1 = p[e]; i1 = e; }
  float v2 = -1.f; int i2 = 0;
#pragma unroll
  for (int e = 0; e < NE; ++e) if (e != i1 && p[e] > v2) { v2 = p[e]; i2 = e; }
  float s1 = v1 / sum, s2 = v2 / sum;
  float dn = s1 + s2 + 1e-20f;
  float w1 = s1 / dn * LSCALE, w2 = s2 / dn * LSCALE;
  if ((tid & 15) < 8) {
    int el = tid & 7;
    wl[r][el] = (el == i1) ? w1 : ((el == i2) ? w2 : 0.f);
  }
  barrier_lds();                        // wl visible

  // scale + store low to GLOBAL (token=lrow, cols=lk*4+j).  e=(wv&1)*4+ct
#pragma unroll
  for (int ct = 0; ct < 4; ++ct) {
    int col = wv * 64 + ct * 16 + lk * 4;
    int ccol = col & 127;
    short* op = (col < 128) ? lowq : lowv;
    float wgt = wl[lrow][(wv & 1) * 4 + ct];
    s16x4 v;
#pragma unroll
    for (int j = 0; j < 4; ++j) v[j] = f2bf(acc1[ct][j] * wgt);
    *(s16x4*)(op + (size_t)(row0 + lrow) * 128 + ccol) = v;
  }
}

// ---------------------------------------------------------------------------
// Stage 2: delta = low[T,128] @ B[128,2048].  32-tok x 256-col blocks,
// grid (T/32, 16) = 8192 blocks -> wave-slot-limited occupancy (~8 waves/
// SIMD possible at ~50 VGPR + 32 AGPR), NOT grid-limited (R8-R13 bug).
// K=128 = 4 fully-unrolled MFMA steps; depth-1 B prefetch; NT stores.
// ---------------------------------------------------------------------------
__global__ __launch_bounds__(256) void k_up(
    const short* __restrict__ lowq, const short* __restrict__ lowv,
    const short* __restrict__ Bq2, const short* __restrict__ Bv2,
    float* __restrict__ out) {
  const int lane = threadIdx.x & 63, wv = threadIdx.x >> 6;
  const int lrow = lane & 15, lk = lane >> 4;
  const int row0 = blockIdx.x * 32;
  const int m = blockIdx.y >> 3;
  const int cb = (blockIdx.y & 7) * 256 + wv * 64;
  const short* low = m ? lowv : lowq;
  const short* B = m ? Bv2 : Bq2;
  float* op = out + (size_t)m * T_TOKENS * QOUT;

  s16x8 a[2][4];
#pragma unroll
  for (int rt = 0; rt < 2; ++rt)
#pragma unroll
    for (int kk = 0; kk < 4; ++kk)
      a[rt][kk] = *(const s16x8*)(low + (size_t)(row0 + rt * 16 + lrow) * 128 + kk * 32 + lk * 8);

  s16x8 bc[4], bn[4];
#pragma unroll
  for (int ct = 0; ct < 4; ++ct) {
    int c = cb + ct * 16 + lrow;
    bc[ct] = *(const s16x8*)(B + ((size_t)lk * QOUT + c) * 8);
  }

  f32x4 acc[2][4] = {};
#pragma unroll
  for (int kk = 0; kk < 4; ++kk) {
    const int kkn = (kk + 1) & 3;          // dead value on last iter
#pragma unroll
    for (int ct = 0; ct < 4; ++ct) {
      int c = cb + ct * 16 + lrow;
      bn[ct] = *(const s16x8*)(B + ((size_t)(kkn * 4 + lk) * QOUT + c) * 8);
    }
#pragma unroll
    for (int rt = 0; rt < 2; ++rt)
#pragma unroll
      for (int ct = 0; ct < 4; ++ct)
        acc[rt][ct] = __builtin_amdgcn_mfma_f32_16x16x32_bf16(bc[ct], a[rt][kk], acc[rt][ct], 0, 0, 0);
#pragma unroll
    for (int ct = 0; ct < 4; ++ct) bc[ct] = bn[ct];
  }
#pragma unroll
  for (int rt = 0; rt < 2; ++rt)
#pragma unroll
    for (int ct = 0; ct < 4; ++ct) {
      int t = row0 + rt * 16 + lrow;
      int col = cb + ct * 16 + lk * 4;
      __builtin_nontemporal_store(acc[rt][ct], (f32x4*)(op + (size_t)t * QOUT + col));
    }
}

extern "C" void kernel_launch(void* const* d_in, const int* in_sizes, int n_in,
                              void* d_out, int out_size, void* d_ws, size_t ws_size,
                              hipStream_t stream) {
  const float* h  = (const float*)d_in[0];
  const float* rw = (const float*)d_in[1];
  const float* qa = (const float*)d_in[2];
  const float* qb = (const float*)d_in[3];
  const float* va = (const float*)d_in[4];
  const float* vb = (const float*)d_in[5];
  float* out = (float*)d_out;
  char* ws = (char*)d_ws;

  short* Bq1 = (short*)(ws);                    // 512 KB each
  short* Bv1 = (short*)(ws + (512 << 10));
  short* Bq2 = (short*)(ws + (1024 << 10));
  short* Bv2 = (short*)(ws + (1536 << 10));
  short* lowq = (short*)(ws + (2 << 20));       // 4 MB each
  short* lowv = (short*)(ws + (6 << 20));

  k_pack<<<512, 256, 0, stream>>>(qa, qb, va, vb, Bq1, Bv1, Bq2, Bv2);
  k_s1<<<T_TOKENS / 16, 256, 0, stream>>>(h, rw, Bq1, Bv1, lowq, lowv);
  dim3 g2(T_TOKENS / 32, 16);
  k_up<<<g2, 256, 0, stream>>>(lowq, lowv, Bq2, Bv2, out);
}